// Round 2
// baseline (606.906 us; speedup 1.0000x reference)
//
#include <hip/hip_runtime.h>
#include <hip/hip_bf16.h>

// EdgeDecoder: out[e] = relu(concat(zu[row[e]], zr[col[e]]) @ W1 + b1) @ W2 + b2
// R2 strategy: gather-GEMM on v_mfma_f32_32x32x16_bf16, with
//   - Pre-pass: z_user/z_recipe fp32 -> bf16 into d_ws (38.4 MB). Halves the
//     1 GB gather volume and cache footprint; kills in-loop v_cvt.
//   - Main: 512-thread blocks (8 waves share the 64 KB LDS W1 tile -> 2
//     blocks/CU = 16 waves/CU), MT=1 (32 edges/wave/sweep, acc = 64 VGPRs so
//     4 waves/SIMD fit), index prefetch one sweep ahead.
//   - A-fragment (verified R1): A[m=lane&31][k=(lane>>5)*8+j] = one dwordx4
//     from the gathered bf16 row. B pre-swizzled in LDS, one ds_read_b128.
//   - C/D (verified R1): col=lane&31, row=(reg&3)+8*(reg>>2)+4*(lane>>5).
//   - Fused epilogue: +b1, relu, *W2, 5-step shfl_xor butterfly, +b2, store.

#define HDIM 128

typedef __attribute__((ext_vector_type(8))) __bf16 bf16x8;
typedef __attribute__((ext_vector_type(16))) float f32x16;

static __device__ __forceinline__ unsigned short bf16_bits(float x) {
  return __builtin_bit_cast(unsigned short, static_cast<__bf16>(x));
}

static __device__ __forceinline__ bf16x8 cvt8(float4 a, float4 b) {
  bf16x8 r;
  r[0] = static_cast<__bf16>(a.x);
  r[1] = static_cast<__bf16>(a.y);
  r[2] = static_cast<__bf16>(a.z);
  r[3] = static_cast<__bf16>(a.w);
  r[4] = static_cast<__bf16>(b.x);
  r[5] = static_cast<__bf16>(b.y);
  r[6] = static_cast<__bf16>(b.z);
  r[7] = static_cast<__bf16>(b.w);
  return r;
}

// ---------- pre-pass: fp32 -> bf16 (both tables, concatenated in d_ws) ------
__global__ void cvt_to_bf16(const float* __restrict__ a, int na,
                            const float* __restrict__ b, int nb,
                            unsigned short* __restrict__ dst) {
  const int n8 = (na + nb) >> 3;  // both multiples of 8 (rows of 128)
  for (int i = blockIdx.x * blockDim.x + threadIdx.x; i < n8;
       i += gridDim.x * blockDim.x) {
    const int base = i << 3;
    const float* src = (base < na) ? (a + base) : (b + (base - na));
    const float4* s4 = (const float4*)src;
    const bf16x8 v = cvt8(s4[0], s4[1]);
    ((uint4*)dst)[i] = __builtin_bit_cast(uint4, v);
  }
}

// ---------- main kernel: bf16 gather-GEMM, MT=1, 512 threads ---------------
__global__ __launch_bounds__(512, 4) void edge_decoder_bf16(
    const unsigned short* __restrict__ zub, const unsigned short* __restrict__ zrb,
    const int* __restrict__ eidx, const float* __restrict__ W1,
    const float* __restrict__ b1, const float* __restrict__ W2,
    const float* __restrict__ b2, float* __restrict__ out, int E) {
  // W1 as bf16 in B-fragment order: Bsw[((kc*4+nt)*64+lane)*8+j]
  //   with k = kc*16 + (lane>>5)*8 + j, n = nt*32 + (lane&31)
  __shared__ unsigned short Bsw[32768];  // 64 KB

  const int tid = threadIdx.x;
  {
    const int n = tid & 127;
    const int kh = tid >> 7;  // 0..3
    const int nt = n >> 5;
    const int nl = n & 31;
#pragma unroll 8
    for (int it = 0; it < 64; ++it) {
      const int k = (it << 2) + kh;
      const float w = W1[k * HDIM + n];
      const int kc = k >> 4;
      const int q = (k >> 3) & 1;
      const int j = k & 7;
      const int ln = (q << 5) | nl;
      Bsw[((((kc << 2) + nt) << 6) | ln) * 8 + j] = bf16_bits(w);
    }
  }
  __syncthreads();

  const int lane = tid & 63;
  const int wid = tid >> 6;   // 0..7
  const int m = lane & 31;    // edge row within 32-tile
  const int half = lane >> 5;
  const int koff = half * 8;  // bf16-element offset within 16-wide k-chunk
  const int nsweep = E >> 5;  // 32 edges per sweep
  const int wstride = gridDim.x * 8;

  float b1v[4], w2v[4];
#pragma unroll
  for (int nt = 0; nt < 4; ++nt) {
    b1v[nt] = b1[nt * 32 + m];
    w2v[nt] = W2[nt * 32 + m];
  }
  const float b2v = b2[0];

  int s = blockIdx.x * 8 + wid;
  if (s >= nsweep) return;
  int iu = eidx[(s << 5) + m];
  int ir = eidx[E + (s << 5) + m];

  while (s < nsweep) {
    const int ns = s + wstride;
    const int np = (ns < nsweep) ? ns : s;  // clamped prefetch address
    const unsigned short* pu = zub + (size_t)iu * HDIM + koff;
    const unsigned short* pr = zrb + (size_t)ir * HDIM + koff;
    const int niu = eidx[(np << 5) + m];
    const int nir = eidx[E + (np << 5) + m];

    f32x16 acc[4];
#pragma unroll
    for (int nt = 0; nt < 4; ++nt) acc[nt] = (f32x16)0.0f;

#pragma unroll
    for (int kc = 0; kc < 16; ++kc) {
      const unsigned short* src = (kc < 8) ? (pu + kc * 16) : (pr + (kc - 8) * 16);
      const bf16x8 a = __builtin_bit_cast(bf16x8, *(const uint4*)src);
#pragma unroll
      for (int nt = 0; nt < 4; ++nt) {
        const uint4* bp = (const uint4*)(Bsw + ((((kc << 2) + nt) << 6) | lane) * 8);
        const bf16x8 bfr = __builtin_bit_cast(bf16x8, *bp);
        acc[nt] = __builtin_amdgcn_mfma_f32_32x32x16_bf16(a, bfr, acc[nt], 0, 0, 0);
      }
    }

    // Epilogue: p[r] = sum over all 128 h-cols of relu(acc+b1)*W2.
    float p[16];
#pragma unroll
    for (int r = 0; r < 16; ++r) p[r] = 0.f;
#pragma unroll
    for (int nt = 0; nt < 4; ++nt) {
#pragma unroll
      for (int r = 0; r < 16; ++r) {
        const float h = fmaxf(acc[nt][r] + b1v[nt], 0.f);
        p[r] = fmaf(h, w2v[nt], p[r]);
      }
    }
#pragma unroll
    for (int st = 1; st <= 16; st <<= 1) {
#pragma unroll
      for (int r = 0; r < 16; ++r) p[r] += __shfl_xor(p[r], st);
    }
    const int sel = lane & 15;
    float val = 0.f;
#pragma unroll
    for (int r = 0; r < 16; ++r) val = (sel == r) ? p[r] : val;
    if ((lane & 16) == 0) {
      const int mrow = (sel & 3) + ((sel >> 2) << 3) + (half << 2);
      out[(s << 5) + mrow] = val + b2v;
    }

    s = ns;
    iu = niu;
    ir = nir;
  }
}

// ---------- fallback (R1 kernel, fp32 gathers, no workspace) ---------------
__global__ __launch_bounds__(256, 2) void edge_decoder_mfma(
    const float* __restrict__ zu, const float* __restrict__ zr,
    const int* __restrict__ eidx, const float* __restrict__ W1,
    const float* __restrict__ b1, const float* __restrict__ W2,
    const float* __restrict__ b2, float* __restrict__ out, int E) {
  __shared__ unsigned short Bsw[32768];
  const int tid = threadIdx.x;
  {
    const int n = tid & 127;
    const int kh = tid >> 7;
    const int nt = n >> 5;
    const int nl = n & 31;
#pragma unroll 8
    for (int it = 0; it < 128; ++it) {
      const int k = 2 * it + kh;
      const float w = W1[k * HDIM + n];
      const int kc = k >> 4;
      const int q = (k >> 3) & 1;
      const int j = k & 7;
      const int ln = (q << 5) | nl;
      Bsw[((((kc << 2) + nt) << 6) | ln) * 8 + j] = bf16_bits(w);
    }
  }
  __syncthreads();

  const int lane = tid & 63;
  const int wid = tid >> 6;
  const int m = lane & 31;
  const int half = lane >> 5;
  const int nsweep = E >> 6;
  const int wstride = gridDim.x * 4;

  float b1v[4], w2v[4];
#pragma unroll
  for (int nt = 0; nt < 4; ++nt) {
    b1v[nt] = b1[nt * 32 + m];
    w2v[nt] = W2[nt * 32 + m];
  }
  const float b2v = b2[0];
  const int koff = half * 8;

  for (int s = blockIdx.x * 4 + wid; s < nsweep; s += wstride) {
    const int e0 = s << 6;
    const int eA = e0 + m;
    const int eB = e0 + 32 + m;
    const float* puA = zu + (size_t)eidx[eA] * HDIM;
    const float* prA = zr + (size_t)eidx[E + eA] * HDIM;
    const float* puB = zu + (size_t)eidx[eB] * HDIM;
    const float* prB = zr + (size_t)eidx[E + eB] * HDIM;

    f32x16 acc[2][4];
#pragma unroll
    for (int mt = 0; mt < 2; ++mt)
#pragma unroll
      for (int nt = 0; nt < 4; ++nt) acc[mt][nt] = (f32x16)0.0f;

#pragma unroll
    for (int kc = 0; kc < 16; ++kc) {
      const float* srcA = (kc < 8) ? (puA + kc * 16 + koff) : (prA + (kc - 8) * 16 + koff);
      const float* srcB = (kc < 8) ? (puB + kc * 16 + koff) : (prB + (kc - 8) * 16 + koff);
      const float4* sa = (const float4*)srcA;
      const float4* sb = (const float4*)srcB;
      const bf16x8 a0 = cvt8(sa[0], sa[1]);
      const bf16x8 a1 = cvt8(sb[0], sb[1]);
#pragma unroll
      for (int nt = 0; nt < 4; ++nt) {
        const uint4* bp = (const uint4*)(Bsw + ((((kc << 2) + nt) << 6) | lane) * 8);
        const bf16x8 bfr = __builtin_bit_cast(bf16x8, *bp);
        acc[0][nt] = __builtin_amdgcn_mfma_f32_32x32x16_bf16(a0, bfr, acc[0][nt], 0, 0, 0);
        acc[1][nt] = __builtin_amdgcn_mfma_f32_32x32x16_bf16(a1, bfr, acc[1][nt], 0, 0, 0);
      }
    }

    float p0[16], p1[16];
#pragma unroll
    for (int r = 0; r < 16; ++r) { p0[r] = 0.f; p1[r] = 0.f; }
#pragma unroll
    for (int nt = 0; nt < 4; ++nt) {
#pragma unroll
      for (int r = 0; r < 16; ++r) {
        float h0 = fmaxf(acc[0][nt][r] + b1v[nt], 0.f);
        float h1 = fmaxf(acc[1][nt][r] + b1v[nt], 0.f);
        p0[r] = fmaf(h0, w2v[nt], p0[r]);
        p1[r] = fmaf(h1, w2v[nt], p1[r]);
      }
    }
#pragma unroll
    for (int st = 1; st <= 16; st <<= 1) {
#pragma unroll
      for (int r = 0; r < 16; ++r) {
        p0[r] += __shfl_xor(p0[r], st);
        p1[r] += __shfl_xor(p1[r], st);
      }
    }
    const int sel = lane & 15;
    const int mtw = (lane >> 4) & 1;
    float val = 0.f;
#pragma unroll
    for (int r = 0; r < 16; ++r) {
      const float cand = mtw ? p1[r] : p0[r];
      val = (sel == r) ? cand : val;
    }
    const int mrow = (sel & 3) + ((sel >> 2) << 3) + (half << 2);
    out[e0 + (mtw << 5) + mrow] = val + b2v;
  }
}

extern "C" void kernel_launch(void* const* d_in, const int* in_sizes, int n_in,
                              void* d_out, int out_size, void* d_ws,
                              size_t ws_size, hipStream_t stream) {
  const float* zu = (const float*)d_in[0];
  const float* zr = (const float*)d_in[1];
  const int* eidx = (const int*)d_in[2];
  const float* W1 = (const float*)d_in[3];
  const float* b1 = (const float*)d_in[4];
  const float* W2 = (const float*)d_in[5];
  const float* b2 = (const float*)d_in[6];
  float* out = (float*)d_out;
  const int nu = in_sizes[0];        // N_USER * 128
  const int nr = in_sizes[1];        // N_RECIPE * 128
  const int E = in_sizes[2] / 2;     // 1,000,000

  const size_t need = (size_t)(nu + nr) * sizeof(unsigned short);
  if (ws_size >= need) {
    unsigned short* zb = (unsigned short*)d_ws;
    hipLaunchKernelGGL(cvt_to_bf16, dim3(1024), dim3(256), 0, stream,
                       zu, nu, zr, nr, zb);
    // zb[0..nu) = z_user bf16, zb[nu..nu+nr) = z_recipe bf16
    hipLaunchKernelGGL(edge_decoder_bf16, dim3(512), dim3(512), 0, stream,
                       zb, zb + nu, eidx, W1, b1, W2, b2, out, E);
  } else {
    hipLaunchKernelGGL(edge_decoder_mfma, dim3(512), dim3(256), 0, stream,
                       zu, zr, eidx, W1, b1, W2, b2, out, E);
  }
}

// Round 3
// 195.352 us; speedup vs baseline: 3.1067x; 3.1067x over previous
//
#include <hip/hip_runtime.h>
#include <hip/hip_bf16.h>

// EdgeDecoder: out[e] = relu(concat(zu[row[e]], zr[col[e]]) @ W1 + b1) @ W2 + b2
// R3 strategy: factor the edge GEMM through per-node projections.
//   Pass 1 (proj_nodes, MFMA): Hu = zu @ W1[:128], Hr = zr @ W1[128:], stored
//     bf16 in d_ws (38.4 MB). Dense streaming GEMM, no gather. Reuses the
//     R1-verified Bsw LDS layout + A-fragment + C/D mapping.
//   Pass 2 (edge_pass): out[e] = relu(Hu[row]+Hr[col]+b1) . W2 + b2.
//     16 lanes per edge x 16 B = one fully-coalesced 256 B row per quarter-
//     wave; each L2 line is consumed whole by a single instruction (fixes the
//     R1/R2 pattern where every instruction touched 64 scattered rows).
//     No LDS, low VGPR -> high occupancy; 2-edge unroll + index prefetch.

#define HDIM 128

typedef __attribute__((ext_vector_type(8))) __bf16 bf16x8;
typedef __attribute__((ext_vector_type(16))) float f32x16;

static __device__ __forceinline__ unsigned short bf16_bits(float x) {
  return __builtin_bit_cast(unsigned short, static_cast<__bf16>(x));
}

static __device__ __forceinline__ float bf2f(unsigned short u) {
  return __builtin_bit_cast(float, ((unsigned int)u) << 16);
}

static __device__ __forceinline__ bf16x8 cvt8(float4 a, float4 b) {
  bf16x8 r;
  r[0] = static_cast<__bf16>(a.x);
  r[1] = static_cast<__bf16>(a.y);
  r[2] = static_cast<__bf16>(a.z);
  r[3] = static_cast<__bf16>(a.w);
  r[4] = static_cast<__bf16>(b.x);
  r[5] = static_cast<__bf16>(b.y);
  r[6] = static_cast<__bf16>(b.z);
  r[7] = static_cast<__bf16>(b.w);
  return r;
}

// ---------- pass 1: node projections (dense MFMA GEMM, no gather) ----------
__global__ __launch_bounds__(256, 2) void proj_nodes(
    const float* __restrict__ zu, int NU, const float* __restrict__ zr, int NR,
    const float* __restrict__ W1, unsigned short* __restrict__ Hu,
    unsigned short* __restrict__ Hr) {
  // W1 bf16, B-fragment order: Bsw[((kc*4+nt)*64+lane)*8+j],
  //   k = kc*16 + (lane>>5)*8 + j, n = nt*32 + (lane&31). kc 0..7 = W1[:128]
  //   (user half), kc 8..15 = W1[128:] (recipe half).
  __shared__ unsigned short Bsw[32768];
  const int tid = threadIdx.x;
  {
    const int n = tid & 127;
    const int kh = tid >> 7;
    const int nt = n >> 5;
    const int nl = n & 31;
#pragma unroll 8
    for (int it = 0; it < 128; ++it) {
      const int k = 2 * it + kh;
      const float w = W1[k * HDIM + n];
      const int kc = k >> 4;
      const int q = (k >> 3) & 1;
      const int j = k & 7;
      const int ln = (q << 5) | nl;
      Bsw[((((kc << 2) + nt) << 6) | ln) * 8 + j] = bf16_bits(w);
    }
  }
  __syncthreads();

  const int lane = tid & 63;
  const int wid = tid >> 6;
  const int m = lane & 31;
  const int half = lane >> 5;
  const int koff = half * 8;
  const int utiles = NU >> 5;          // 3125 (NU divisible by 32)
  const int rtiles = (NR + 31) >> 5;   // 1563 (tail handled by clamp/predicate)
  const int ntiles = utiles + rtiles;
  const int wstride = gridDim.x * 4;

  for (int t = blockIdx.x * 4 + wid; t < ntiles; t += wstride) {
    const bool isU = t < utiles;
    const int base = isU ? (t << 5) : ((t - utiles) << 5);
    const int nmax = isU ? NU : NR;
    int node = base + m;
    if (node >= nmax) node = nmax - 1;  // clamped read for tail tile
    const float* src = (isU ? zu : zr) + (size_t)node * HDIM + koff;
    const int kc0 = isU ? 0 : 8;

    f32x16 acc[4];
#pragma unroll
    for (int nt = 0; nt < 4; ++nt) acc[nt] = (f32x16)0.0f;

#pragma unroll
    for (int kcl = 0; kcl < 8; ++kcl) {
      const float4* sa = (const float4*)(src + kcl * 16);
      const bf16x8 a = cvt8(sa[0], sa[1]);
#pragma unroll
      for (int nt = 0; nt < 4; ++nt) {
        const uint4* bp =
            (const uint4*)(Bsw + (((((kc0 + kcl) << 2) + nt) << 6) | lane) * 8);
        const bf16x8 bfr = __builtin_bit_cast(bf16x8, *bp);
        acc[nt] = __builtin_amdgcn_mfma_f32_32x32x16_bf16(a, bfr, acc[nt], 0, 0, 0);
      }
    }

    unsigned short* H = isU ? Hu : Hr;
#pragma unroll
    for (int nt = 0; nt < 4; ++nt) {
#pragma unroll
      for (int r = 0; r < 16; ++r) {
        const int row = (r & 3) + ((r >> 2) << 3) + (half << 2);
        const int nrow = base + row;
        if (nrow < nmax)
          H[(size_t)nrow * HDIM + (nt << 5) + m] = bf16_bits(acc[nt][r]);
      }
    }
  }
}

// ---------- pass 2: gather + relu + dot(W2) ---------------------------------
static __device__ __forceinline__ float dot8(uint4 a, uint4 b,
                                             const float* b1c,
                                             const float* w2c) {
  const unsigned short* pa = (const unsigned short*)&a;
  const unsigned short* pb = (const unsigned short*)&b;
  float s = 0.f;
#pragma unroll
  for (int j = 0; j < 8; ++j) {
    const float h = bf2f(pa[j]) + bf2f(pb[j]) + b1c[j];
    s = fmaf(fmaxf(h, 0.f), w2c[j], s);
  }
  return s;
}

__global__ __launch_bounds__(256, 4) void edge_pass(
    const unsigned short* __restrict__ Hu, const unsigned short* __restrict__ Hr,
    const int* __restrict__ eidx, const float* __restrict__ b1,
    const float* __restrict__ W2, const float* __restrict__ b2,
    float* __restrict__ out, int E) {
  const int tid = threadIdx.x;
  const int lane = tid & 63;
  const int c = lane & 15;   // 16 B chunk within the 256 B row
  const int g = lane >> 4;   // edge-group within wave (4 groups)
  const int wid = blockIdx.x * 4 + (tid >> 6);
  const int stride = gridDim.x * 4 * 8;  // 8 edges per wave per iteration

  float b1c[8], w2c[8];
#pragma unroll
  for (int j = 0; j < 8; ++j) {
    b1c[j] = b1[c * 8 + j];
    w2c[j] = W2[c * 8 + j];
  }
  const float b2v = b2[0];

  int e = wid * 8 + g * 2;  // wave covers 8 consecutive edges (E % 8 == 0)
  if (e >= E) return;
  int iu0 = eidx[e], ir0 = eidx[E + e];
  int iu1 = eidx[e + 1], ir1 = eidx[E + e + 1];

  while (true) {
    const int en = e + stride;
    const bool more = en < E;
    const int ep = more ? en : e;

    const uint4 au0 = *(const uint4*)(Hu + (size_t)iu0 * HDIM + c * 8);
    const uint4 ar0 = *(const uint4*)(Hr + (size_t)ir0 * HDIM + c * 8);
    const uint4 au1 = *(const uint4*)(Hu + (size_t)iu1 * HDIM + c * 8);
    const uint4 ar1 = *(const uint4*)(Hr + (size_t)ir1 * HDIM + c * 8);

    const int niu0 = eidx[ep], nir0 = eidx[E + ep];
    const int niu1 = eidx[ep + 1], nir1 = eidx[E + ep + 1];

    float s0 = dot8(au0, ar0, b1c, w2c);
    float s1 = dot8(au1, ar1, b1c, w2c);
#pragma unroll
    for (int st = 1; st <= 8; st <<= 1) {
      s0 += __shfl_xor(s0, st);
      s1 += __shfl_xor(s1, st);
    }
    if (c == 0) {
      out[e] = s0 + b2v;
      out[e + 1] = s1 + b2v;
    }
    if (!more) break;
    e = en;
    iu0 = niu0; ir0 = nir0; iu1 = niu1; ir1 = nir1;
  }
}

// ---------- fallback (R1 kernel, fp32 gathers, no workspace) ---------------
__global__ __launch_bounds__(256, 2) void edge_decoder_mfma(
    const float* __restrict__ zu, const float* __restrict__ zr,
    const int* __restrict__ eidx, const float* __restrict__ W1,
    const float* __restrict__ b1, const float* __restrict__ W2,
    const float* __restrict__ b2, float* __restrict__ out, int E) {
  __shared__ unsigned short Bsw[32768];
  const int tid = threadIdx.x;
  {
    const int n = tid & 127;
    const int kh = tid >> 7;
    const int nt = n >> 5;
    const int nl = n & 31;
#pragma unroll 8
    for (int it = 0; it < 128; ++it) {
      const int k = 2 * it + kh;
      const float w = W1[k * HDIM + n];
      const int kc = k >> 4;
      const int q = (k >> 3) & 1;
      const int j = k & 7;
      const int ln = (q << 5) | nl;
      Bsw[((((kc << 2) + nt) << 6) | ln) * 8 + j] = bf16_bits(w);
    }
  }
  __syncthreads();

  const int lane = tid & 63;
  const int wid = tid >> 6;
  const int m = lane & 31;
  const int half = lane >> 5;
  const int nsweep = E >> 6;
  const int wstride = gridDim.x * 4;

  float b1v[4], w2v[4];
#pragma unroll
  for (int nt = 0; nt < 4; ++nt) {
    b1v[nt] = b1[nt * 32 + m];
    w2v[nt] = W2[nt * 32 + m];
  }
  const float b2v = b2[0];
  const int koff = half * 8;

  for (int s = blockIdx.x * 4 + wid; s < nsweep; s += wstride) {
    const int e0 = s << 6;
    const int eA = e0 + m;
    const int eB = e0 + 32 + m;
    const float* puA = zu + (size_t)eidx[eA] * HDIM;
    const float* prA = zr + (size_t)eidx[E + eA] * HDIM;
    const float* puB = zu + (size_t)eidx[eB] * HDIM;
    const float* prB = zr + (size_t)eidx[E + eB] * HDIM;

    f32x16 acc[2][4];
#pragma unroll
    for (int mt = 0; mt < 2; ++mt)
#pragma unroll
      for (int nt = 0; nt < 4; ++nt) acc[mt][nt] = (f32x16)0.0f;

#pragma unroll
    for (int kc = 0; kc < 16; ++kc) {
      const float* srcA = (kc < 8) ? (puA + kc * 16 + koff) : (prA + (kc - 8) * 16 + koff);
      const float* srcB = (kc < 8) ? (puB + kc * 16 + koff) : (prB + (kc - 8) * 16 + koff);
      const float4* sa = (const float4*)srcA;
      const float4* sb = (const float4*)srcB;
      const bf16x8 a0 = cvt8(sa[0], sa[1]);
      const bf16x8 a1 = cvt8(sb[0], sb[1]);
#pragma unroll
      for (int nt = 0; nt < 4; ++nt) {
        const uint4* bp = (const uint4*)(Bsw + ((((kc << 2) + nt) << 6) | lane) * 8);
        const bf16x8 bfr = __builtin_bit_cast(bf16x8, *bp);
        acc[0][nt] = __builtin_amdgcn_mfma_f32_32x32x16_bf16(a0, bfr, acc[0][nt], 0, 0, 0);
        acc[1][nt] = __builtin_amdgcn_mfma_f32_32x32x16_bf16(a1, bfr, acc[1][nt], 0, 0, 0);
      }
    }

    float p0[16], p1[16];
#pragma unroll
    for (int r = 0; r < 16; ++r) { p0[r] = 0.f; p1[r] = 0.f; }
#pragma unroll
    for (int nt = 0; nt < 4; ++nt) {
#pragma unroll
      for (int r = 0; r < 16; ++r) {
        float h0 = fmaxf(acc[0][nt][r] + b1v[nt], 0.f);
        float h1 = fmaxf(acc[1][nt][r] + b1v[nt], 0.f);
        p0[r] = fmaf(h0, w2v[nt], p0[r]);
        p1[r] = fmaf(h1, w2v[nt], p1[r]);
      }
    }
#pragma unroll
    for (int st = 1; st <= 16; st <<= 1) {
#pragma unroll
      for (int r = 0; r < 16; ++r) {
        p0[r] += __shfl_xor(p0[r], st);
        p1[r] += __shfl_xor(p1[r], st);
      }
    }
    const int sel = lane & 15;
    const int mtw = (lane >> 4) & 1;
    float val = 0.f;
#pragma unroll
    for (int r = 0; r < 16; ++r) {
      const float cand = mtw ? p1[r] : p0[r];
      val = (sel == r) ? cand : val;
    }
    const int mrow = (sel & 3) + ((sel >> 2) << 3) + (half << 2);
    out[e0 + (mtw << 5) + mrow] = val + b2v;
  }
}

extern "C" void kernel_launch(void* const* d_in, const int* in_sizes, int n_in,
                              void* d_out, int out_size, void* d_ws,
                              size_t ws_size, hipStream_t stream) {
  const float* zu = (const float*)d_in[0];
  const float* zr = (const float*)d_in[1];
  const int* eidx = (const int*)d_in[2];
  const float* W1 = (const float*)d_in[3];
  const float* b1 = (const float*)d_in[4];
  const float* W2 = (const float*)d_in[5];
  const float* b2 = (const float*)d_in[6];
  float* out = (float*)d_out;
  const int nu = in_sizes[0];     // N_USER * 128
  const int nr = in_sizes[1];     // N_RECIPE * 128
  const int E = in_sizes[2] / 2;  // 1,000,000
  const int NU = nu / HDIM, NR = nr / HDIM;

  const size_t need = (size_t)(nu + nr) * sizeof(unsigned short);
  if (ws_size >= need) {
    unsigned short* Hu = (unsigned short*)d_ws;
    unsigned short* Hr = Hu + (size_t)nu;
    hipLaunchKernelGGL(proj_nodes, dim3(512), dim3(256), 0, stream,
                       zu, NU, zr, NR, W1, Hu, Hr);
    hipLaunchKernelGGL(edge_pass, dim3(2048), dim3(256), 0, stream,
                       Hu, Hr, eidx, b1, W2, b2, out, E);
  } else {
    hipLaunchKernelGGL(edge_decoder_mfma, dim3(512), dim3(256), 0, stream,
                       zu, zr, eidx, W1, b1, W2, b2, out, E);
  }
}